// Round 1
// 457.235 us; speedup vs baseline: 1.0510x; 1.0510x over previous
//
#include <hip/hip_runtime.h>
#include <hip/hip_bf16.h>

typedef __attribute__((ext_vector_type(8))) short short8;
typedef __attribute__((ext_vector_type(4))) float float4v;

// fp32 -> bf16 round-to-nearest-even (finite inputs only)
__device__ inline unsigned short f2bf(float f) {
    union { float f; unsigned int i; } c; c.f = f;
    unsigned int r = c.i + 0x7FFFu + ((c.i >> 16) & 1u);
    return (unsigned short)(r >> 16);
}

// ---------------------------------------------------------------------------
// Kernel 1: build Wt in FRAGMENT-LINEAR layout.
// k_main wants, per (d-half dh, chunk c, wave w, ks, nt), the 64-lane MFMA
// B-fragment as one contiguous 1KB run:  lane holds B[k=kb..kb+7][d],
// d = dh*256 + w*64 + nt*16 + (lane&15),  kb = c*64 + ks*32 + (lane>>4)*8.
// Index:  idx = dh<<15 | c<<11 | w<<9 | ks<<8 | nt<<6 | lane ; 8 shorts @ idx*8.
// This turns k_main's B reads into perfectly coalesced streaming dwordx4.
// ---------------------------------------------------------------------------
__global__ void k_transpose(const float* __restrict__ W,
                            unsigned short* __restrict__ Wt) {
    int idx  = blockIdx.x * 256 + threadIdx.x;   // 65536 threads
    int lane = idx & 63;
    int nt   = (idx >> 6) & 3;
    int ks   = (idx >> 8) & 1;
    int w    = (idx >> 9) & 3;
    int c    = (idx >> 11) & 15;
    int dh   = (idx >> 15) & 1;
    int d  = dh * 256 + w * 64 + nt * 16 + (lane & 15);
    int kb = c * 64 + ks * 32 + (lane >> 4) * 8;
    short8 v;
#pragma unroll
    for (int j = 0; j < 8; j++)
        v[j] = (short)f2bf(W[(size_t)(512 + kb + j) * 512 + d]); // coalesced over d
    *(short8*)(Wt + (size_t)idx * 8) = v;
}

// ---------------------------------------------------------------------------
// Kernel 2: hb[b][d] = hidden[b,:] @ W[0:512, d] + bias[d]   (all fp32)
// ---------------------------------------------------------------------------
__global__ void k_hb(const float* __restrict__ hidden,
                     const float* __restrict__ W,
                     const float* __restrict__ bias,
                     float* __restrict__ hb) {
    int b = blockIdx.x, d = threadIdx.x;   // 512 threads
    __shared__ float h[512];
    h[d] = hidden[b * 512 + d];
    __syncthreads();
    float a = 0.f;
#pragma unroll 8
    for (int k = 0; k < 512; k++)
        a += h[k] * W[(size_t)k * 512 + d];
    hb[b * 512 + d] = a + bias[d];
}

// ---------------------------------------------------------------------------
// Kernel 3: fused GEMM(enc @ W_e) + tanh(.+hb) . v  partial reduction.
// Grid (dh=2, 16 s-tiles, 64 b); block 256 = 4 waves.
// Each block owns 256 d-columns (dh half); wave w owns d in [w*64,(w+1)*64).
// acc[4][4] = 64 AGPR (vs 128 before) -> 3 waves/SIMD target (launch_bounds 3).
// B fragments stream coalesced from fragment-linear Wt (no scattered loads).
// Per-chunk issue order: B loads -> A prefetch -> MFMA (vmcnt FIFO friendly).
// ---------------------------------------------------------------------------
__launch_bounds__(256, 3)
__global__ void k_main(const float* __restrict__ enc,
                       const unsigned short* __restrict__ Wt,
                       const float* __restrict__ hb,
                       const float* __restrict__ vvec,
                       float* __restrict__ att) {
    const int dh   = blockIdx.x;           // 0..1 d-half
    const int s0   = blockIdx.y * 64;      // 16 s-tiles
    const int b    = blockIdx.z;
    const int tid  = threadIdx.x;
    const int wave = tid >> 6;
    const int lane = tid & 63;
    const int col  = lane & 15;   // n (B) / m (A) index
    const int quad = lane >> 4;   // k-group: k = quad*8 + j

    // A-tile: 64 rows x 64 k bf16, +8 pad -> row stride 144B
    __shared__ unsigned short As[2][64][72];

    // Staging map: thread t -> row r = t>>2, col-quarter cq = t&3 (16 floats)
    const int r  = tid >> 2;
    const int cq = tid & 3;
    int s = s0 + r; if (s > 999) s = 999;          // dup rows masked at output
    const float* arow = enc + ((size_t)(b * 1000 + s) * 1024 + cq * 16);

    // B stream base: fragment-linear Wt (see k_transpose)
    const unsigned short* bbase = Wt + (size_t)dh * 262144 + wave * 4096 + lane * 8;

    float4v acc[4][4];
#pragma unroll
    for (int mt = 0; mt < 4; mt++)
#pragma unroll
        for (int nt = 0; nt < 4; nt++)
            acc[mt][nt] = float4v{0.f, 0.f, 0.f, 0.f};

    // ---- prologue: stage chunk 0 ----
    float4v st[4];
#pragma unroll
    for (int j = 0; j < 4; j++) st[j] = *(const float4v*)(arow + j * 4);
    {
        short8 wv0, wv1;
#pragma unroll
        for (int j = 0; j < 4; j++) {
            wv0[j]     = (short)f2bf(st[0][j]);
            wv0[j + 4] = (short)f2bf(st[1][j]);
            wv1[j]     = (short)f2bf(st[2][j]);
            wv1[j + 4] = (short)f2bf(st[3][j]);
        }
        unsigned short* wp = &As[0][r][cq * 16];
        *(short8*)(wp)     = wv0;
        *(short8*)(wp + 8) = wv1;
    }
    __syncthreads();

    // ---- main K loop: 16 chunks of 64 ----
    for (int c = 0; c < 16; c++) {
        const int buf = c & 1;

        // B fragments FIRST: 8 coalesced 16B loads from a contiguous 32KB block
        short8 bf[2][4];
#pragma unroll
        for (int ks = 0; ks < 2; ks++)
#pragma unroll
            for (int nt = 0; nt < 4; nt++)
                bf[ks][nt] = *(const short8*)(bbase + c * 16384 + (ks * 4 + nt) * 512);

        // A prefetch AFTER B loads: waiting on bf never drains these HBM loads
        if (c < 15) {
#pragma unroll
            for (int j = 0; j < 4; j++)
                st[j] = *(const float4v*)(arow + (c + 1) * 64 + j * 4);
        }

#pragma unroll
        for (int ks = 0; ks < 2; ks++) {
            short8 af[4];
#pragma unroll
            for (int mt = 0; mt < 4; mt++)
                af[mt] = *(const short8*)(&As[buf][mt * 16 + col][ks * 32 + quad * 8]);
#pragma unroll
            for (int mt = 0; mt < 4; mt++)
#pragma unroll
                for (int nt = 0; nt < 4; nt++)
                    acc[mt][nt] = __builtin_amdgcn_mfma_f32_16x16x32_bf16(
                        af[mt], bf[ks][nt], acc[mt][nt], 0, 0, 0);
        }

        // convert + write next chunk into the other buffer
        if (c < 15) {
            short8 wv0, wv1;
#pragma unroll
            for (int j = 0; j < 4; j++) {
                wv0[j]     = (short)f2bf(st[0][j]);
                wv0[j + 4] = (short)f2bf(st[1][j]);
                wv1[j]     = (short)f2bf(st[2][j]);
                wv1[j + 4] = (short)f2bf(st[3][j]);
            }
            unsigned short* wq = &As[buf ^ 1][r][cq * 16];
            *(short8*)(wq)     = wv0;
            *(short8*)(wq + 8) = wv1;
        }
        __syncthreads();
    }

    // ---- epilogue: partial[m] += tanh(e + hb) * v over this wave's 64 d's
    float vv[4], hbv[4];
#pragma unroll
    for (int nt = 0; nt < 4; nt++) {
        int d = dh * 256 + wave * 64 + nt * 16 + col;
        vv[nt]  = vvec[d];
        hbv[nt] = hb[b * 512 + d];
    }
    float rs[4][4];   // [mt][rg] -> row m = mt*16 + quad*4 + rg
#pragma unroll
    for (int mt = 0; mt < 4; mt++)
#pragma unroll
        for (int rg = 0; rg < 4; rg++) rs[mt][rg] = 0.f;

#pragma unroll
    for (int mt = 0; mt < 4; mt++)
#pragma unroll
        for (int nt = 0; nt < 4; nt++)
#pragma unroll
            for (int rg = 0; rg < 4; rg++) {
                float e = acc[mt][nt][rg] + hbv[nt];
                float t = 1.f - 2.f / (__expf(2.f * e) + 1.f);   // tanh
                rs[mt][rg] += t * vv[nt];
            }

#pragma unroll
    for (int mt = 0; mt < 4; mt++)
#pragma unroll
        for (int rg = 0; rg < 4; rg++) {
            float x = rs[mt][rg];
            x += __shfl_xor(x, 1);
            x += __shfl_xor(x, 2);
            x += __shfl_xor(x, 4);
            x += __shfl_xor(x, 8);
            rs[mt][rg] = x;
        }

    __shared__ float red[4][64];
    if (col == 0) {
#pragma unroll
        for (int mt = 0; mt < 4; mt++)
#pragma unroll
            for (int rg = 0; rg < 4; rg++)
                red[wave][mt * 16 + quad * 4 + rg] = rs[mt][rg];
    }
    __syncthreads();
    if (tid < 64) {
        float sum = red[0][tid] + red[1][tid] + red[2][tid] + red[3][tid];
        int ss = s0 + tid;
        if (ss < 1000) att[(size_t)dh * 64000 + b * 1000 + ss] = sum;
    }
}

// ---------------------------------------------------------------------------
// Kernel 4: row softmax over S=1000 (sums the two d-half partials), fp32 out.
// ---------------------------------------------------------------------------
__global__ void k_softmax(const float* __restrict__ att,
                          float* __restrict__ out) {
    int b = blockIdx.x, tid = threadIdx.x;
    __shared__ float sm[4], ss[4];
    float x[4], mx = -1e30f;
#pragma unroll
    for (int i = 0; i < 4; i++) {
        int s = tid + 256 * i;
        if (s < 1000) {
            x[i] = att[b * 1000 + s] + att[64000 + b * 1000 + s];
        } else {
            x[i] = -1e30f;
        }
        mx = fmaxf(mx, x[i]);
    }
    for (int off = 1; off < 64; off <<= 1) mx = fmaxf(mx, __shfl_xor(mx, off));
    if ((tid & 63) == 0) sm[tid >> 6] = mx;
    __syncthreads();
    mx = fmaxf(fmaxf(sm[0], sm[1]), fmaxf(sm[2], sm[3]));

    float ex[4], se = 0.f;
#pragma unroll
    for (int i = 0; i < 4; i++) {
        ex[i] = __expf(x[i] - mx);
        if (tid + 256 * i >= 1000) ex[i] = 0.f;
        se += ex[i];
    }
    for (int off = 1; off < 64; off <<= 1) se += __shfl_xor(se, off);
    if ((tid & 63) == 0) ss[tid >> 6] = se;
    __syncthreads();
    se = ss[0] + ss[1] + ss[2] + ss[3];
    float inv = 1.f / se;
#pragma unroll
    for (int i = 0; i < 4; i++) {
        int s = tid + 256 * i;
        if (s < 1000) out[b * 1000 + s] = ex[i] * inv;
    }
}

// ---------------------------------------------------------------------------
extern "C" void kernel_launch(void* const* d_in, const int* in_sizes, int n_in,
                              void* d_out, int out_size, void* d_ws, size_t ws_size,
                              hipStream_t stream) {
    const float* hidden = (const float*)d_in[0]; // [64,512]
    const float* enc    = (const float*)d_in[1]; // [64,1000,1024]
    const float* attn_w = (const float*)d_in[2]; // [1536,512]
    const float* attn_b = (const float*)d_in[3]; // [512]
    const float* v      = (const float*)d_in[4]; // [512]
    float* out = (float*)d_out;                  // [64,1000]

    char* ws = (char*)d_ws;
    unsigned short* Wt = (unsigned short*)ws;                       // 1 MB bf16 (fragment-linear)
    float* hb  = (float*)(ws + (1 << 20));                          // 128 KB
    float* att = (float*)(ws + (1 << 20) + (128 << 10));            // 500 KB (2 halves)

    k_transpose<<<256, 256, 0, stream>>>(attn_w, Wt);
    k_hb<<<64, 512, 0, stream>>>(hidden, attn_w, attn_b, hb);
    k_main<<<dim3(2, 16, 64), 256, 0, stream>>>(enc, Wt, hb, v, att);
    k_softmax<<<64, 256, 0, stream>>>(att, out);
}

// Round 2
// 446.640 us; speedup vs baseline: 1.0759x; 1.0237x over previous
//
#include <hip/hip_runtime.h>
#include <hip/hip_bf16.h>

typedef __attribute__((ext_vector_type(8))) short short8;
typedef __attribute__((ext_vector_type(4))) float float4v;
typedef __attribute__((ext_vector_type(4))) int int4v;

// fp32 -> bf16 round-to-nearest-even (finite inputs only)
__device__ inline unsigned short f2bf(float f) {
    union { float f; unsigned int i; } c; c.f = f;
    unsigned int r = c.i + 0x7FFFu + ((c.i >> 16) & 1u);
    return (unsigned short)(r >> 16);
}

// pack 8 fp32 -> 8 bf16 via v_cvt_pk_bf16_f32 (RNE), MFMA fragment order
__device__ inline short8 cvt8(float4v lo, float4v hi) {
    int p0, p1, p2, p3;
    asm("v_cvt_pk_bf16_f32 %0, %1, %2" : "=v"(p0) : "v"(lo[0]), "v"(lo[1]));
    asm("v_cvt_pk_bf16_f32 %0, %1, %2" : "=v"(p1) : "v"(lo[2]), "v"(lo[3]));
    asm("v_cvt_pk_bf16_f32 %0, %1, %2" : "=v"(p2) : "v"(hi[0]), "v"(hi[1]));
    asm("v_cvt_pk_bf16_f32 %0, %1, %2" : "=v"(p3) : "v"(hi[2]), "v"(hi[3]));
    int4v w; w[0] = p0; w[1] = p1; w[2] = p2; w[3] = p3;
    union { int4v i; short8 s; } u; u.i = w;
    return u.s;
}

typedef __attribute__((address_space(1))) const void gas_t;
typedef __attribute__((address_space(3))) void las_t;

// ---------------------------------------------------------------------------
// Kernel 1: build Wt in FRAGMENT-LINEAR layout (unchanged).
// idx = dh<<15 | c<<11 | w<<9 | ks<<8 | nt<<6 | lane ; 8 shorts @ idx*8.
// lane holds B[k=kb..kb+7][d], d = dh*256 + w*64 + nt*16 + (lane&15),
// kb = c*64 + ks*32 + (lane>>4)*8.
// ---------------------------------------------------------------------------
__global__ void k_transpose(const float* __restrict__ W,
                            unsigned short* __restrict__ Wt) {
    int idx  = blockIdx.x * 256 + threadIdx.x;   // 65536 threads
    int lane = idx & 63;
    int nt   = (idx >> 6) & 3;
    int ks   = (idx >> 8) & 1;
    int w    = (idx >> 9) & 3;
    int c    = (idx >> 11) & 15;
    int dh   = (idx >> 15) & 1;
    int d  = dh * 256 + w * 64 + nt * 16 + (lane & 15);
    int kb = c * 64 + ks * 32 + (lane >> 4) * 8;
    short8 v;
#pragma unroll
    for (int j = 0; j < 8; j++)
        v[j] = (short)f2bf(W[(size_t)(512 + kb + j) * 512 + d]); // coalesced over d
    *(short8*)(Wt + (size_t)idx * 8) = v;
}

// ---------------------------------------------------------------------------
// Kernel 2: hb[b][d] = hidden[b,:] @ W[0:512, d] + bias[d]   (all fp32)
// ---------------------------------------------------------------------------
__global__ void k_hb(const float* __restrict__ hidden,
                     const float* __restrict__ W,
                     const float* __restrict__ bias,
                     float* __restrict__ hb) {
    int b = blockIdx.x, d = threadIdx.x;   // 512 threads
    __shared__ float h[512];
    h[d] = hidden[b * 512 + d];
    __syncthreads();
    float a = 0.f;
#pragma unroll 8
    for (int k = 0; k < 512; k++)
        a += h[k] * W[(size_t)k * 512 + d];
    hb[b * 512 + d] = a + bias[d];
}

// ---------------------------------------------------------------------------
// Kernel 3: fused GEMM(enc @ W_e) + tanh(.+hb) . v  partial reduction.
// Grid (dh=2, 16 s-tiles, 64 b); block 256 = 4 waves.
// A staged as RAW FP32 via global_load_lds (async, no VGPR round trip, no
// f2bf staging pass). LDS tile [64][64] fp32, XOR-swizzled in 16B granules:
//   LDS[row][slot] holds global slot^(row&7)  (write: pre-swizzled global
//   source column; read: same XOR on ds_read_b128 address)  -> 2 lanes/bank.
// fp32->bf16 conversion at fragment-read time via v_cvt_pk_bf16_f32.
// Per-chunk issue order: B frag loads -> global_load_lds(c+1) -> compute,
// so MFMA's vmcnt wait on B leaves the LDS prefetch in flight.
// ---------------------------------------------------------------------------
__launch_bounds__(256, 3)
__global__ void k_main(const float* __restrict__ enc,
                       const unsigned short* __restrict__ Wt,
                       const float* __restrict__ hb,
                       const float* __restrict__ vvec,
                       float* __restrict__ att) {
    const int dh   = blockIdx.x;           // 0..1 d-half
    const int s0   = blockIdx.y * 64;      // 16 s-tiles
    const int b    = blockIdx.z;
    const int tid  = threadIdx.x;
    const int wave = tid >> 6;
    const int lane = tid & 63;
    const int col  = lane & 15;   // n (B) / m (A) index
    const int quad = lane >> 4;   // k-group: k = quad*8 + j

    // A-tile: double-buffered raw fp32 [64][64], linear (global_load_lds dest)
    __shared__ float Asf[2][64][64];
    __shared__ float red[4][64];

    // ---- staging per-lane constants (4 global_load_lds per wave per chunk)
    // inst j, lane l -> tile row r = wave*16 + j*4 + (l>>4),
    // LDS 16B-slot (l&15); its global 16B-slot = (l&15) ^ (r&7).
    const float* gbase0; const float* gbase1;
    const float* gbase2; const float* gbase3;
    {
        int l4 = lane >> 4;
#pragma unroll
        for (int j = 0; j < 4; j++) {
            int r = wave * 16 + j * 4 + l4;
            int s = s0 + r; if (s > 999) s = 999;       // dup rows, masked at output
            int slot = (lane & 15) ^ (r & 7);
            const float* p = enc + ((size_t)(b * 1000 + s) * 1024) + slot * 4;
            if (j == 0) gbase0 = p; else if (j == 1) gbase1 = p;
            else if (j == 2) gbase2 = p; else gbase3 = p;
        }
    }

    // B stream base: fragment-linear Wt (see k_transpose)
    const unsigned short* bbase = Wt + (size_t)dh * 262144 + wave * 4096 + lane * 8;

    float4v acc[4][4];
#pragma unroll
    for (int mt = 0; mt < 4; mt++)
#pragma unroll
        for (int nt = 0; nt < 4; nt++)
            acc[mt][nt] = float4v{0.f, 0.f, 0.f, 0.f};

#define STAGE(nbuf, koff)                                                     \
    do {                                                                      \
        las_t* d0 = (las_t*)&Asf[nbuf][wave * 16 + 0][0];                     \
        las_t* d1 = (las_t*)&Asf[nbuf][wave * 16 + 4][0];                     \
        las_t* d2 = (las_t*)&Asf[nbuf][wave * 16 + 8][0];                     \
        las_t* d3 = (las_t*)&Asf[nbuf][wave * 16 + 12][0];                    \
        __builtin_amdgcn_global_load_lds((gas_t*)(gbase0 + (koff)), d0, 16, 0, 0); \
        __builtin_amdgcn_global_load_lds((gas_t*)(gbase1 + (koff)), d1, 16, 0, 0); \
        __builtin_amdgcn_global_load_lds((gas_t*)(gbase2 + (koff)), d2, 16, 0, 0); \
        __builtin_amdgcn_global_load_lds((gas_t*)(gbase3 + (koff)), d3, 16, 0, 0); \
    } while (0)

    // ---- prologue: stage chunk 0 ----
    STAGE(0, 0);
    __syncthreads();

    // ---- main K loop: 16 chunks of 64 ----
    for (int c = 0; c < 16; c++) {
        const int buf = c & 1;

        // B fragments FIRST: 8 coalesced 16B loads (contiguous 8KB/wave)
        short8 bf[2][4];
#pragma unroll
        for (int ks = 0; ks < 2; ks++)
#pragma unroll
            for (int nt = 0; nt < 4; nt++)
                bf[ks][nt] = *(const short8*)(bbase + c * 16384 + (ks * 4 + nt) * 512);

        // async-stage next chunk AFTER B issues: vmcnt wait on B keeps these in flight
        if (c < 15) STAGE(buf ^ 1, (c + 1) * 64);

#pragma unroll
        for (int ks = 0; ks < 2; ks++) {
            // raw fp32 fragment reads (swizzled) then pack to bf16
            float4v r0[4], r1[4];
#pragma unroll
            for (int mt = 0; mt < 4; mt++) {
                int row = mt * 16 + col;
                int rsw = row & 7;
                int sl0 = (ks * 8 + quad * 2 + 0) ^ rsw;
                int sl1 = (ks * 8 + quad * 2 + 1) ^ rsw;
                r0[mt] = *(const float4v*)(&Asf[buf][row][sl0 * 4]);
                r1[mt] = *(const float4v*)(&Asf[buf][row][sl1 * 4]);
            }
#pragma unroll
            for (int mt = 0; mt < 4; mt++) {
                short8 af = cvt8(r0[mt], r1[mt]);
#pragma unroll
                for (int nt = 0; nt < 4; nt++)
                    acc[mt][nt] = __builtin_amdgcn_mfma_f32_16x16x32_bf16(
                        af, bf[ks][nt], acc[mt][nt], 0, 0, 0);
            }
        }
        __syncthreads();   // drains gload_lds(c+1); buf roles swap
    }
#undef STAGE

    // ---- epilogue: partial[m] += tanh(e + hb) * v over this wave's 64 d's
    float vv[4], hbv[4];
#pragma unroll
    for (int nt = 0; nt < 4; nt++) {
        int d = dh * 256 + wave * 64 + nt * 16 + col;
        vv[nt]  = vvec[d];
        hbv[nt] = hb[b * 512 + d];
    }
    float rs[4][4];   // [mt][rg] -> row m = mt*16 + quad*4 + rg
#pragma unroll
    for (int mt = 0; mt < 4; mt++)
#pragma unroll
        for (int rg = 0; rg < 4; rg++) rs[mt][rg] = 0.f;

#pragma unroll
    for (int mt = 0; mt < 4; mt++)
#pragma unroll
        for (int nt = 0; nt < 4; nt++)
#pragma unroll
            for (int rg = 0; rg < 4; rg++) {
                float e = acc[mt][nt][rg] + hbv[nt];
                float t = 1.f - 2.f / (__expf(2.f * e) + 1.f);   // tanh
                rs[mt][rg] += t * vv[nt];
            }

#pragma unroll
    for (int mt = 0; mt < 4; mt++)
#pragma unroll
        for (int rg = 0; rg < 4; rg++) {
            float x = rs[mt][rg];
            x += __shfl_xor(x, 1);
            x += __shfl_xor(x, 2);
            x += __shfl_xor(x, 4);
            x += __shfl_xor(x, 8);
            rs[mt][rg] = x;
        }

    if (col == 0) {
#pragma unroll
        for (int mt = 0; mt < 4; mt++)
#pragma unroll
            for (int rg = 0; rg < 4; rg++)
                red[wave][mt * 16 + quad * 4 + rg] = rs[mt][rg];
    }
    __syncthreads();
    if (tid < 64) {
        float sum = red[0][tid] + red[1][tid] + red[2][tid] + red[3][tid];
        int ss = s0 + tid;
        if (ss < 1000) att[(size_t)dh * 64000 + b * 1000 + ss] = sum;
    }
}

// ---------------------------------------------------------------------------
// Kernel 4: row softmax over S=1000 (sums the two d-half partials), fp32 out.
// ---------------------------------------------------------------------------
__global__ void k_softmax(const float* __restrict__ att,
                          float* __restrict__ out) {
    int b = blockIdx.x, tid = threadIdx.x;
    __shared__ float sm[4], ss[4];
    float x[4], mx = -1e30f;
#pragma unroll
    for (int i = 0; i < 4; i++) {
        int s = tid + 256 * i;
        if (s < 1000) {
            x[i] = att[b * 1000 + s] + att[64000 + b * 1000 + s];
        } else {
            x[i] = -1e30f;
        }
        mx = fmaxf(mx, x[i]);
    }
    for (int off = 1; off < 64; off <<= 1) mx = fmaxf(mx, __shfl_xor(mx, off));
    if ((tid & 63) == 0) sm[tid >> 6] = mx;
    __syncthreads();
    mx = fmaxf(fmaxf(sm[0], sm[1]), fmaxf(sm[2], sm[3]));

    float ex[4], se = 0.f;
#pragma unroll
    for (int i = 0; i < 4; i++) {
        ex[i] = __expf(x[i] - mx);
        if (tid + 256 * i >= 1000) ex[i] = 0.f;
        se += ex[i];
    }
    for (int off = 1; off < 64; off <<= 1) se += __shfl_xor(se, off);
    if ((tid & 63) == 0) ss[tid >> 6] = se;
    __syncthreads();
    se = ss[0] + ss[1] + ss[2] + ss[3];
    float inv = 1.f / se;
#pragma unroll
    for (int i = 0; i < 4; i++) {
        int s = tid + 256 * i;
        if (s < 1000) out[b * 1000 + s] = ex[i] * inv;
    }
}

// ---------------------------------------------------------------------------
extern "C" void kernel_launch(void* const* d_in, const int* in_sizes, int n_in,
                              void* d_out, int out_size, void* d_ws, size_t ws_size,
                              hipStream_t stream) {
    const float* hidden = (const float*)d_in[0]; // [64,512]
    const float* enc    = (const float*)d_in[1]; // [64,1000,1024]
    const float* attn_w = (const float*)d_in[2]; // [1536,512]
    const float* attn_b = (const float*)d_in[3]; // [512]
    const float* v      = (const float*)d_in[4]; // [512]
    float* out = (float*)d_out;                  // [64,1000]

    char* ws = (char*)d_ws;
    unsigned short* Wt = (unsigned short*)ws;                       // 1 MB bf16 (fragment-linear)
    float* hb  = (float*)(ws + (1 << 20));                          // 128 KB
    float* att = (float*)(ws + (1 << 20) + (128 << 10));            // 500 KB (2 halves)

    k_transpose<<<256, 256, 0, stream>>>(attn_w, Wt);
    k_hb<<<64, 512, 0, stream>>>(hidden, attn_w, attn_b, hb);
    k_main<<<dim3(2, 16, 64), 256, 0, stream>>>(enc, Wt, hb, v, att);
    k_softmax<<<64, 256, 0, stream>>>(att, out);
}